// Round 3
// baseline (61.512 us; speedup 1.0000x reference)
//
#include <hip/hip_runtime.h>
#include <math.h>

#define BB 256
#define DD 12288
#define LL 32
#define NPXB 1536                    // px blocks: each covers 512 float4 per array
#define GRID (NPXB + BB)             // 1792
#define LOG2PI_F 1.8378770664093453f
#define BETA_F 6.0f

// ws layout (floats): [0 .. NPXB-1]      px partial sums of (lv + dx^2*e^-lv)
//                     [2048 .. 2303]     per-i pairwise term t[i]
//                     uint at index 4096 trigger counter (any start value OK)

__global__ __launch_bounds__(256) void tcvae_fused(
    const float* __restrict__ target,
    const float* __restrict__ x_mean,
    const float* __restrict__ x_log_var,
    const float* __restrict__ z,
    const float* __restrict__ z_mean,
    const float* __restrict__ z_log_var,
    float* __restrict__ ws, float* __restrict__ out, float log_nm)
{
    const int tid = threadIdx.x;
    const int bid = blockIdx.x;

    __shared__ float ch[8][257];     // chunked transpose buffer (8.2 KB)
    __shared__ float red[8];
    __shared__ float lse_l[LL];
    __shared__ float sd2[LL];
    __shared__ float misc[2];
    __shared__ int   isLast;

    const int wid = tid >> 6, lane = tid & 63;

    if (bid >= BB) {
        // ---------------- px path: 512 consecutive float4 per array ----------
        const size_t base = (size_t)(bid - BB) * 512;
        const float4* t4 = (const float4*)target    + base;
        const float4* m4 = (const float4*)x_mean    + base;
        const float4* v4 = (const float4*)x_log_var + base;
        float4 x0 = t4[tid], x1 = t4[tid + 256];
        float4 m0 = m4[tid], m1 = m4[tid + 256];
        float4 l0 = v4[tid], l1 = v4[tid + 256];
        float dx, acc = 0.f;
        dx = x0.x - m0.x; acc += l0.x + dx * dx * __expf(-l0.x);
        dx = x0.y - m0.y; acc += l0.y + dx * dx * __expf(-l0.y);
        dx = x0.z - m0.z; acc += l0.z + dx * dx * __expf(-l0.z);
        dx = x0.w - m0.w; acc += l0.w + dx * dx * __expf(-l0.w);
        dx = x1.x - m1.x; acc += l1.x + dx * dx * __expf(-l1.x);
        dx = x1.y - m1.y; acc += l1.y + dx * dx * __expf(-l1.y);
        dx = x1.z - m1.z; acc += l1.z + dx * dx * __expf(-l1.z);
        dx = x1.w - m1.w; acc += l1.w + dx * dx * __expf(-l1.w);
        #pragma unroll
        for (int o = 32; o; o >>= 1) acc += __shfl_xor(acc, o, 64);
        if (lane == 0) red[wid] = acc;
        __syncthreads();
        if (tid == 0) ws[bid - BB] = red[0] + red[1] + red[2] + red[3];
    } else {
        // ---------------- pairwise path for sample i --------------------------
        const int i = bid;

        if (tid < 64) {
            float pz = 0.f, qzx = 0.f;
            if (tid < LL) {
                float zl  = z[i * LL + tid];
                float zm  = z_mean[i * LL + tid];
                float lvi = z_log_var[i * LL + tid];
                float d   = zl - zm;
                float d2  = d * d;
                sd2[tid]  = d2;
                pz  = -0.5f * (LOG2PI_F + zl * zl);
                qzx = -0.5f * (LOG2PI_F + lvi + d2 * __expf(-lvi));
            }
            #pragma unroll
            for (int o = 32; o; o >>= 1) {
                pz  += __shfl_xor(pz,  o, 64);
                qzx += __shfl_xor(qzx, o, 64);
            }
            if (tid == 0) { misc[0] = pz; misc[1] = qzx; }
        }
        __syncthreads();

        // thread j: M[i,j,l] for l=0..31 in registers
        const int j = tid;
        const float4* lv4 = (const float4*)(z_log_var + j * LL);
        float mv[32];
        float s_j = 0.f;
        #pragma unroll
        for (int qq = 0; qq < 8; ++qq) {
            float4 lv = lv4[qq];
            const int l0i = qq * 4;
            float A, e, v;
            A = -0.5f * (LOG2PI_F + lv.x); e = __expf(-lv.x);
            v = A - 0.5f * sd2[l0i + 0] * e; mv[l0i + 0] = v; s_j += v;
            A = -0.5f * (LOG2PI_F + lv.y); e = __expf(-lv.y);
            v = A - 0.5f * sd2[l0i + 1] * e; mv[l0i + 1] = v; s_j += v;
            A = -0.5f * (LOG2PI_F + lv.z); e = __expf(-lv.z);
            v = A - 0.5f * sd2[l0i + 2] * e; mv[l0i + 2] = v; s_j += v;
            A = -0.5f * (LOG2PI_F + lv.w); e = __expf(-lv.w);
            v = A - 0.5f * sd2[l0i + 3] * e; mv[l0i + 3] = v; s_j += v;
        }

        // block LSE over j of s_j -> log_qz
        float mx = s_j;
        #pragma unroll
        for (int o = 32; o; o >>= 1) mx = fmaxf(mx, __shfl_xor(mx, o, 64));
        if (lane == 0) red[wid] = mx;
        __syncthreads();
        mx = fmaxf(fmaxf(red[0], red[1]), fmaxf(red[2], red[3]));
        float es = __expf(s_j - mx);
        #pragma unroll
        for (int o = 32; o; o >>= 1) es += __shfl_xor(es, o, 64);
        if (lane == 0) red[4 + wid] = es;
        __syncthreads();
        const float log_qz = mx + __logf(red[4] + red[5] + red[6] + red[7]) - log_nm;

        // chunked per-l LSE: 4 chunks x 8 rows; 32 threads per row (8 j's each)
        const int lrow = tid >> 5;       // 0..7
        const int k    = tid & 31;       // 0..31
        #pragma unroll
        for (int c = 0; c < 4; ++c) {
            __syncthreads();             // ch free (first iter: after red use)
            #pragma unroll
            for (int r = 0; r < 8; ++r) ch[r][j] = mv[c * 8 + r];
            __syncthreads();
            float vv[8];
            float m2 = -INFINITY;
            #pragma unroll
            for (int mm = 0; mm < 8; ++mm) {
                vv[mm] = ch[lrow][k + 32 * mm];
                m2 = fmaxf(m2, vv[mm]);
            }
            #pragma unroll
            for (int o = 16; o; o >>= 1) m2 = fmaxf(m2, __shfl_xor(m2, o, 64));
            float se = 0.f;
            #pragma unroll
            for (int mm = 0; mm < 8; ++mm) se += __expf(vv[mm] - m2);
            #pragma unroll
            for (int o = 16; o; o >>= 1) se += __shfl_xor(se, o, 64);
            if (k == 0) lse_l[c * 8 + lrow] = m2 + __logf(se);
        }
        __syncthreads();

        if (tid < 64) {
            float v = (tid < LL) ? lse_l[tid] : 0.f;
            #pragma unroll
            for (int o = 32; o; o >>= 1) v += __shfl_xor(v, o, 64);
            if (tid == 0) {
                const float log_qz_prod = v - (float)LL * log_nm;
                const float t = misc[0] - misc[1]
                              + (1.f - BETA_F) * log_qz
                              + (BETA_F - 1.f) * log_qz_prod;
                ws[2048 + i] = t;
            }
        }
    }

    // ---------------- last-block finisher --------------------------------------
    if (tid == 0) {
        __threadfence();
        unsigned old = atomicAdd((unsigned*)ws + 4096, 1u);
        isLast = ((old % (unsigned)GRID) == (unsigned)(GRID - 1)) ? 1 : 0;
    }
    __syncthreads();
    if (isLast) {
        __threadfence();
        volatile float* w = ws;
        float s = 0.f;
        #pragma unroll
        for (int q = 0; q < 6; ++q) s += w[tid + 256 * q];   // 1536 px partials
        float t = w[2048 + tid];                             // 256 pairwise terms
        #pragma unroll
        for (int o = 32; o; o >>= 1) {
            s += __shfl_xor(s, o, 64);
            t += __shfl_xor(t, o, 64);
        }
        if (lane == 0) { red[wid] = s; red[4 + wid] = t; }
        __syncthreads();
        if (tid == 0) {
            const float S_px = red[0] + red[1] + red[2] + red[3];
            const float T    = red[4] + red[5] + red[6] + red[7];
            const float log_px_sum = -0.5f * ((float)BB * (float)DD * LOG2PI_F + S_px);
            out[0] = -(log_px_sum + T) * (1.0f / (float)BB);
        }
    }
}

extern "C" void kernel_launch(void* const* d_in, const int* in_sizes, int n_in,
                              void* d_out, int out_size, void* d_ws, size_t ws_size,
                              hipStream_t stream) {
    const float* target    = (const float*)d_in[0];
    const float* x_mean    = (const float*)d_in[1];
    const float* x_log_var = (const float*)d_in[2];
    const float* z         = (const float*)d_in[3];
    const float* z_mean    = (const float*)d_in[4];
    const float* z_log_var = (const float*)d_in[5];
    float* ws  = (float*)d_ws;
    float* out = (float*)d_out;

    const float log_nm = logf((float)BB * 202599.0f);

    tcvae_fused<<<GRID, 256, 0, stream>>>(target, x_mean, x_log_var,
                                          z, z_mean, z_log_var, ws, out, log_nm);
}

// Round 4
// 15.209 us; speedup vs baseline: 4.0443x; 4.0443x over previous
//
#include <hip/hip_runtime.h>
#include <math.h>

#define BB 256
#define DD 12288
#define LL 32
#define NPXB 1536                    // px blocks: each covers 512 float4 per array
#define LOG2PI_F 1.8378770664093453f
#define BETA_F 6.0f

// ws layout (floats): [0 .. NPXB-1]   px partial sums of (lv + dx^2*e^-lv)
//                     [2048 .. 2303]  per-i pairwise term t[i]

__global__ __launch_bounds__(256) void tcvae_main(
    const float* __restrict__ target,
    const float* __restrict__ x_mean,
    const float* __restrict__ x_log_var,
    const float* __restrict__ z,
    const float* __restrict__ z_mean,
    const float* __restrict__ z_log_var,
    float* __restrict__ ws, float log_nm)
{
    const int tid = threadIdx.x;
    const int bid = blockIdx.x;

    __shared__ float ch[8][257];     // chunked transpose buffer (8.2 KB)
    __shared__ float red[8];
    __shared__ float lse_l[LL];
    __shared__ float sd2[LL];
    __shared__ float misc[2];

    const int wid = tid >> 6, lane = tid & 63;

    if (bid >= BB) {
        // ---------------- px path: 512 consecutive float4 per array ----------
        const size_t base = (size_t)(bid - BB) * 512;
        const float4* t4 = (const float4*)target    + base;
        const float4* m4 = (const float4*)x_mean    + base;
        const float4* v4 = (const float4*)x_log_var + base;
        float4 x0 = t4[tid], x1 = t4[tid + 256];
        float4 m0 = m4[tid], m1 = m4[tid + 256];
        float4 l0 = v4[tid], l1 = v4[tid + 256];
        float dx, acc = 0.f;
        dx = x0.x - m0.x; acc += l0.x + dx * dx * __expf(-l0.x);
        dx = x0.y - m0.y; acc += l0.y + dx * dx * __expf(-l0.y);
        dx = x0.z - m0.z; acc += l0.z + dx * dx * __expf(-l0.z);
        dx = x0.w - m0.w; acc += l0.w + dx * dx * __expf(-l0.w);
        dx = x1.x - m1.x; acc += l1.x + dx * dx * __expf(-l1.x);
        dx = x1.y - m1.y; acc += l1.y + dx * dx * __expf(-l1.y);
        dx = x1.z - m1.z; acc += l1.z + dx * dx * __expf(-l1.z);
        dx = x1.w - m1.w; acc += l1.w + dx * dx * __expf(-l1.w);
        #pragma unroll
        for (int o = 32; o; o >>= 1) acc += __shfl_xor(acc, o, 64);
        if (lane == 0) red[wid] = acc;
        __syncthreads();
        if (tid == 0) ws[bid - BB] = red[0] + red[1] + red[2] + red[3];
        return;
    }

    // ---------------- pairwise path for sample i --------------------------
    const int i = bid;

    if (tid < 64) {
        float pz = 0.f, qzx = 0.f;
        if (tid < LL) {
            float zl  = z[i * LL + tid];
            float zm  = z_mean[i * LL + tid];
            float lvi = z_log_var[i * LL + tid];
            float d   = zl - zm;
            float d2  = d * d;
            sd2[tid]  = d2;
            pz  = -0.5f * (LOG2PI_F + zl * zl);
            qzx = -0.5f * (LOG2PI_F + lvi + d2 * __expf(-lvi));
        }
        #pragma unroll
        for (int o = 32; o; o >>= 1) {
            pz  += __shfl_xor(pz,  o, 64);
            qzx += __shfl_xor(qzx, o, 64);
        }
        if (tid == 0) { misc[0] = pz; misc[1] = qzx; }
    }
    __syncthreads();

    // thread j: M[i,j,l] for l=0..31 in registers
    const int j = tid;
    const float4* lv4 = (const float4*)(z_log_var + j * LL);
    float mv[32];
    float s_j = 0.f;
    #pragma unroll
    for (int qq = 0; qq < 8; ++qq) {
        float4 lv = lv4[qq];
        const int l0i = qq * 4;
        float A, e, v;
        A = -0.5f * (LOG2PI_F + lv.x); e = __expf(-lv.x);
        v = A - 0.5f * sd2[l0i + 0] * e; mv[l0i + 0] = v; s_j += v;
        A = -0.5f * (LOG2PI_F + lv.y); e = __expf(-lv.y);
        v = A - 0.5f * sd2[l0i + 1] * e; mv[l0i + 1] = v; s_j += v;
        A = -0.5f * (LOG2PI_F + lv.z); e = __expf(-lv.z);
        v = A - 0.5f * sd2[l0i + 2] * e; mv[l0i + 2] = v; s_j += v;
        A = -0.5f * (LOG2PI_F + lv.w); e = __expf(-lv.w);
        v = A - 0.5f * sd2[l0i + 3] * e; mv[l0i + 3] = v; s_j += v;
    }

    // block LSE over j of s_j -> log_qz
    float mx = s_j;
    #pragma unroll
    for (int o = 32; o; o >>= 1) mx = fmaxf(mx, __shfl_xor(mx, o, 64));
    if (lane == 0) red[wid] = mx;
    __syncthreads();
    mx = fmaxf(fmaxf(red[0], red[1]), fmaxf(red[2], red[3]));
    float es = __expf(s_j - mx);
    #pragma unroll
    for (int o = 32; o; o >>= 1) es += __shfl_xor(es, o, 64);
    if (lane == 0) red[4 + wid] = es;
    __syncthreads();
    const float log_qz = mx + __logf(red[4] + red[5] + red[6] + red[7]) - log_nm;

    // chunked per-l LSE: 4 chunks x 8 rows; 32 threads per row (8 j's each)
    const int lrow = tid >> 5;       // 0..7
    const int k    = tid & 31;       // 0..31
    #pragma unroll
    for (int c = 0; c < 4; ++c) {
        __syncthreads();             // ch free (first iter: after red use)
        #pragma unroll
        for (int r = 0; r < 8; ++r) ch[r][j] = mv[c * 8 + r];
        __syncthreads();
        float vv[8];
        float m2 = -INFINITY;
        #pragma unroll
        for (int mm = 0; mm < 8; ++mm) {
            vv[mm] = ch[lrow][k + 32 * mm];
            m2 = fmaxf(m2, vv[mm]);
        }
        #pragma unroll
        for (int o = 16; o; o >>= 1) m2 = fmaxf(m2, __shfl_xor(m2, o, 64));
        float se = 0.f;
        #pragma unroll
        for (int mm = 0; mm < 8; ++mm) se += __expf(vv[mm] - m2);
        #pragma unroll
        for (int o = 16; o; o >>= 1) se += __shfl_xor(se, o, 64);
        if (k == 0) lse_l[c * 8 + lrow] = m2 + __logf(se);
    }
    __syncthreads();

    if (tid < 64) {
        float v = (tid < LL) ? lse_l[tid] : 0.f;
        #pragma unroll
        for (int o = 32; o; o >>= 1) v += __shfl_xor(v, o, 64);
        if (tid == 0) {
            const float log_qz_prod = v - (float)LL * log_nm;
            const float t = misc[0] - misc[1]
                          + (1.f - BETA_F) * log_qz
                          + (BETA_F - 1.f) * log_qz_prod;
            ws[2048 + i] = t;
        }
    }
}

// single-wave finisher: 1536 px partials (384 float4) + 256 t's (64 float4)
__global__ __launch_bounds__(64) void tcvae_final(
    const float* __restrict__ ws, float* __restrict__ out)
{
    const int lane = threadIdx.x;
    const float4* w4 = (const float4*)ws;            // ws[0..1535]
    const float4* t4 = (const float4*)(ws + 2048);   // ws[2048..2303]
    float s = 0.f;
    #pragma unroll
    for (int q = 0; q < 6; ++q) {
        float4 w = w4[lane + 64 * q];
        s += w.x + w.y + w.z + w.w;
    }
    float4 tt = t4[lane];
    float t = tt.x + tt.y + tt.z + tt.w;
    #pragma unroll
    for (int o = 32; o; o >>= 1) {
        s += __shfl_xor(s, o, 64);
        t += __shfl_xor(t, o, 64);
    }
    if (lane == 0) {
        const float log_px_sum = -0.5f * ((float)BB * (float)DD * LOG2PI_F + s);
        out[0] = -(log_px_sum + t) * (1.0f / (float)BB);
    }
}

extern "C" void kernel_launch(void* const* d_in, const int* in_sizes, int n_in,
                              void* d_out, int out_size, void* d_ws, size_t ws_size,
                              hipStream_t stream) {
    const float* target    = (const float*)d_in[0];
    const float* x_mean    = (const float*)d_in[1];
    const float* x_log_var = (const float*)d_in[2];
    const float* z         = (const float*)d_in[3];
    const float* z_mean    = (const float*)d_in[4];
    const float* z_log_var = (const float*)d_in[5];
    float* ws  = (float*)d_ws;
    float* out = (float*)d_out;

    const float log_nm = logf((float)BB * 202599.0f);

    tcvae_main<<<BB + NPXB, 256, 0, stream>>>(target, x_mean, x_log_var,
                                              z, z_mean, z_log_var, ws, log_nm);
    tcvae_final<<<1, 64, 0, stream>>>(ws, out);
}